// Round 6
// baseline (83.816 us; speedup 1.0000x reference)
//
#include <hip/hip_runtime.h>
#include <math.h>

#define NBQ 50
#define S1 51
#define NPTS 2601      // 51*51
#define NTILES 163     // ceil(2601/16)
#define IN_D 64
#define HID 128
#define BSZ 256
#define NCHUNK 8

typedef __bf16 bf16x8 __attribute__((ext_vector_type(8)));
typedef float  f32x4  __attribute__((ext_vector_type(4)));
typedef unsigned int u32x4 __attribute__((ext_vector_type(4)));

// ws layout (floats)
#define WS_CC     0                    // 51
#define WS_STEPS  64                   // 51
#define WS_XMAX   128                  // 1
#define WS_SCAL   192                  // 256
#define WS_OFF    448                  // 256
#define WS_PART   704                  // 2048
#define WS_WB     2752                 // 256*128 packed u32 (bf16 w0 | bf16 base)
#define WS_NIW    35520                // 128 packed u32 (bf16 iw2 | bf16 ib1)
#define WS_W1BF   35712                // 16384 bf16 = 8192 floats -> ends 43904

static __device__ inline unsigned int bf16bits(float v) {
    __bf16 t = (__bf16)v;
    return (unsigned int)__builtin_bit_cast(unsigned short, t);
}
static __device__ inline float hi_f32(unsigned int u) {
    return __builtin_bit_cast(float, u & 0xffff0000u);
}
static __device__ inline float lo_f32(unsigned int u) {
    return __builtin_bit_cast(float, u << 16);
}

// ---------------- prep ----------------
// blocks 0..63   : convert iw1 -> bf16 A-fragments
// block  64      : cc/steps/xmax tables + pack (iw2|ib1)
// blocks 65..320 : base[b] (packed with w0) + n-network -> offset/scaling
__global__ void k_prep(const float* __restrict__ x, const float* __restrict__ h,
                       const float* __restrict__ iw0, const float* __restrict__ ib0,
                       const float* __restrict__ iw1, const float* __restrict__ ib1,
                       const float* __restrict__ iw2,
                       const float* __restrict__ nw0, const float* __restrict__ nb0,
                       const float* __restrict__ nw1, const float* __restrict__ nb1,
                       const float* __restrict__ nw2, const float* __restrict__ nb2,
                       float* __restrict__ ws) {
    int blk = blockIdx.x;
    int tid = threadIdx.x;

    if (blk < 64) {
        // A-frag order: idx = ((NT*4+kk)*64 + lane)*8 + e
        //  value = iw1[(kk*32 + (lane>>4)*8 + e)*128 + NT*16 + (lane&15)]
        int idx  = blk * 256 + tid;      // 0..16383
        int e    = idx & 7;
        int lane = (idx >> 3) & 63;
        int fk   = idx >> 9;             // 0..31
        int kk   = fk & 3;
        int nt   = fk >> 2;
        int k = kk * 32 + (lane >> 4) * 8 + e;
        int n = nt * 16 + (lane & 15);
        __bf16* w1bf = (__bf16*)(ws + WS_W1BF);
        w1bf[idx] = (__bf16)iw1[k * HID + n];
        return;
    }

    __shared__ float s_steps[S1];
    __shared__ float s_red[4];
    __shared__ float s_h[IN_D - 1];
    __shared__ float s_o0[HID];
    __shared__ float s_part[4];

    if (blk == 64) {
        int t = tid;
        if (t < HID) {   // pack (iw2 | ib1)
            unsigned int* niw = (unsigned int*)(ws + WS_NIW);
            niw[t] = (bf16bits(iw2[t]) << 16) | bf16bits(ib1[t]);
        }
        if (t < S1) {
            double st = cos((double)t * M_PI / (double)NBQ);
            s_steps[t] = (float)st;
            ws[WS_STEPS + t] = (float)st;
            double acc = 0.0;
            for (int i = 0; i <= NBQ; ++i) {
                double Wi;
                if (i == 0)       Wi = 1.0;
                else if (i & 1)   Wi = 0.0;
                else              Wi = 2.0 / (1.0 - (double)i * (double)i);
                double lam;
                if (t == 0)  lam = 0.5;
                else         lam = cos((double)i * (double)t * M_PI / (double)NBQ);
                if (t == NBQ) lam *= 0.5;
                lam *= 2.0 / (double)NBQ;
                acc += lam * Wi;
            }
            ws[WS_CC + t] = (float)acc;
        }
        __syncthreads();
        float xb = x[t];
        float m = -1e30f;
        for (int i = 0; i < S1; ++i)
            m = fmaxf(m, xb * (s_steps[i] + 1.0f) * 0.5f);
        for (int off = 32; off > 0; off >>= 1)
            m = fmaxf(m, __shfl_down(m, off));
        if ((t & 63) == 0) s_red[t >> 6] = m;
        __syncthreads();
        if (t == 0) {
            float mm = fmaxf(fmaxf(s_red[0], s_red[1]), fmaxf(s_red[2], s_red[3]));
            ws[WS_XMAX] = mm + 10.0f;
        }
        return;
    }

    // ---- base[b] + n-network: b = blk - 65, first 128 threads active ----
    int b = blk - 65;
    int n = tid;
    bool act = (n < HID);
    if (act && n < IN_D - 1) s_h[n] = h[b * (IN_D - 1) + n];
    __syncthreads();
    float o1 = 0.0f;
    if (act) {
        float accB = ib0[n];
        float acc0 = nb0[n];
        for (int d = 0; d < IN_D - 1; ++d) {
            float hv = s_h[d];
            accB = fmaf(hv, iw0[(1 + d) * HID + n], accB);
            acc0 = fmaf(hv, nw0[d * HID + n], acc0);
        }
        // pack (w0 | base)
        unsigned int* wb = (unsigned int*)(ws + WS_WB);
        wb[b * HID + n] = (bf16bits(iw0[n]) << 16) | bf16bits(accB);
        s_o0[n] = fmaxf(acc0, 0.0f);
    }
    __syncthreads();
    if (act) {
        float acc1 = nb1[n];
        for (int m = 0; m < HID; ++m)
            acc1 = fmaf(s_o0[m], nw1[m * HID + n], acc1);
        o1 = fmaxf(acc1, 0.0f);
    }
    float p0 = act ? o1 * nw2[n * 2 + 0] : 0.0f;
    float p1 = act ? o1 * nw2[n * 2 + 1] : 0.0f;
    for (int off = 32; off > 0; off >>= 1) {
        p0 += __shfl_down(p0, off);
        p1 += __shfl_down(p1, off);
    }
    int lane = tid & 63, w = tid >> 6;
    if (lane == 0 && w < 2) { s_part[w * 2] = p0; s_part[w * 2 + 1] = p1; }
    __syncthreads();
    if (tid == 0) {
        ws[WS_OFF + b]  = s_part[0] + s_part[2] + nb2[0];
        ws[WS_SCAL + b] = expf(s_part[1] + s_part[3] + nb2[1]);
    }
}

// ---------------- main MFMA kernel: slim registers -> 2 waves/SIMD ----------
// 1-wave blocks, barrier-free main loop (R3 structure). Cold operands packed
// as bf16 pairs to fit total (VGPR+AGPR) <= 256.
__global__ __launch_bounds__(64, 2) void k3_mfma(
        const float* __restrict__ x,
        const float* __restrict__ ib2p,
        float* __restrict__ ws) {
    __shared__ float s_cc[S1];
    __shared__ float s_ti[S1];
    __shared__ float s_w[S1];
    __shared__ float s_sjh[S1];
    __shared__ float s_ccw[S1];

    int blk  = blockIdx.x;
    int b    = blk >> 3;
    int c    = blk & 7;
    int lane = threadIdx.x;          // 0..63
    int col  = lane & 15;
    int g    = lane >> 4;            // 0..3

    float xmax = ws[WS_XMAX];
    float xb   = x[b];
    float b2   = ib2p[0];

    if (lane < S1) {
        float st = ws[WS_STEPS + lane];
        float cc = ws[WS_CC + lane];
        float ti = xb * (st + 1.0f) * 0.5f;
        float w  = xmax - ti;
        s_cc[lane]  = cc;
        s_ti[lane]  = ti;
        s_w[lane]   = w;
        s_sjh[lane] = (st + 1.0f) * 0.5f;
        s_ccw[lane] = cc * w;
    }

    // W1 A-fragments: 8 nt x 4 kk x 8 bf16 = 128 regs
    const bf16x8* w1f = (const bf16x8*)(ws + WS_W1BF);
    bf16x8 Af[8][4];
#pragma unroll
    for (int nt = 0; nt < 8; ++nt)
#pragma unroll
        for (int kk = 0; kk < 4; ++kk)
            Af[nt][kk] = w1f[(nt * 4 + kk) * 64 + lane];

    // packed (w0|base) for m = kk*32 + g*8 + e : 32 regs
    const unsigned int* wbp = (const unsigned int*)(ws + WS_WB) + b * HID;
    u32x4 wbA[4], wbB[4];
#pragma unroll
    for (int kk = 0; kk < 4; ++kk) {
        int m0 = kk * 32 + g * 8;
        wbA[kk] = *(const u32x4*)(wbp + m0);
        wbB[kk] = *(const u32x4*)(wbp + m0 + 4);
    }

    // packed (iw2|ib1) for n = nt*16 + g*4 + q : 32 regs
    const unsigned int* niw = (const unsigned int*)(ws + WS_NIW);
    u32x4 nv[8];
#pragma unroll
    for (int nt = 0; nt < 8; ++nt)
        nv[nt] = *(const u32x4*)(niw + nt * 16 + g * 4);

    __syncthreads();

    float vsum = 0.0f;

    for (int t = c; t < NTILES; t += NCHUNK) {
        int p  = t * 16 + col;
        int pc = (p < NPTS) ? p : (NPTS - 1);
        int i  = (int)(((unsigned)pc * 10281u) >> 19);   // pc / 51
        int j  = pc - i * 51;
        float s = fmaf(s_w[i], s_sjh[j], s_ti[i]);

        // C-init = ib1 (unpack from pairs directly into acc)
        f32x4 acc[8];
#pragma unroll
        for (int nt = 0; nt < 8; ++nt)
#pragma unroll
            for (int q = 0; q < 4; ++q)
                acc[nt][q] = lo_f32(nv[nt][q]);

#pragma unroll
        for (int kk = 0; kk < 4; ++kk) {
            bf16x8 bfr;
#pragma unroll
            for (int e = 0; e < 4; ++e) {
                unsigned int ua = wbA[kk][e];
                unsigned int ub = wbB[kk][e];
                bfr[e]     = (__bf16)fmaxf(fmaf(s, hi_f32(ua), lo_f32(ua)), 0.0f);
                bfr[4 + e] = (__bf16)fmaxf(fmaf(s, hi_f32(ub), lo_f32(ub)), 0.0f);
            }
#pragma unroll
            for (int nt = 0; nt < 8; ++nt)
                acc[nt] = __builtin_amdgcn_mfma_f32_16x16x32_bf16(
                    Af[nt][kk], bfr, acc[nt], 0, 0, 0);
        }

        // layer2: 4 independent chains of depth 8
        float z0 = 0.f, z1 = 0.f, z2 = 0.f, z3 = 0.f;
#pragma unroll
        for (int nt = 0; nt < 8; ++nt) {
#pragma unroll
            for (int q = 0; q < 4; ++q) {
                float iw2f = hi_f32(nv[nt][q]);
                float v = fmaxf(acc[nt][q], 0.0f);
                if (q == 0)      z0 = fmaf(v, iw2f, z0);
                else if (q == 1) z1 = fmaf(v, iw2f, z1);
                else if (q == 2) z2 = fmaf(v, iw2f, z2);
                else             z3 = fmaf(v, iw2f, z3);
            }
        }
        float z = (z0 + z1) + (z2 + z3);
        z += __shfl_xor(z, 16);
        z += __shfl_xor(z, 32);
        z += b2;
        float ez = __expf(fminf(z, 0.0f));
        float f  = (z > 0.0f) ? (z + 1.0f) : ez;   // elu+1
        float val = s_ccw[i] * s_cc[j] * f;
        vsum += (p < NPTS) ? val : 0.0f;
    }

    // wave reduction; each point counted 4x (g) -> x0.25; inner weight /2 -> x0.125
#pragma unroll
    for (int off = 1; off < 64; off <<= 1)
        vsum += __shfl_xor(vsum, off);
    if (lane == 0)
        ws[WS_PART + blk] = vsum * 0.125f;
}

// ---------------- final: out[b] = scal*(sum parts)*x/2 + off ----------------
__global__ void k4_final(const float* __restrict__ x, const float* __restrict__ ws,
                         float* __restrict__ out) {
    int b = threadIdx.x;
    float sum = 0.0f;
#pragma unroll
    for (int c = 0; c < NCHUNK; ++c) sum += ws[WS_PART + b * NCHUNK + c];
    out[b] = ws[WS_SCAL + b] * sum * x[b] * 0.5f + ws[WS_OFF + b];
}

extern "C" void kernel_launch(void* const* d_in, const int* in_sizes, int n_in,
                              void* d_out, int out_size, void* d_ws, size_t ws_size,
                              hipStream_t stream) {
    const float* x   = (const float*)d_in[0];
    const float* h   = (const float*)d_in[1];
    const float* iw0 = (const float*)d_in[2];
    const float* ib0 = (const float*)d_in[3];
    const float* iw1 = (const float*)d_in[4];
    const float* ib1 = (const float*)d_in[5];
    const float* iw2 = (const float*)d_in[6];
    const float* ib2 = (const float*)d_in[7];
    const float* nw0 = (const float*)d_in[8];
    const float* nb0 = (const float*)d_in[9];
    const float* nw1 = (const float*)d_in[10];
    const float* nb1 = (const float*)d_in[11];
    const float* nw2 = (const float*)d_in[12];
    const float* nb2 = (const float*)d_in[13];
    float* ws  = (float*)d_ws;
    float* out = (float*)d_out;

    hipLaunchKernelGGL(k_prep, dim3(64 + 1 + BSZ), dim3(256), 0, stream,
                       x, h, iw0, ib0, iw1, ib1, iw2, nw0, nb0, nw1, nb1, nw2, nb2, ws);
    hipLaunchKernelGGL(k3_mfma, dim3(BSZ * NCHUNK), dim3(64), 0, stream,
                       x, ib2, ws);
    hipLaunchKernelGGL(k4_final, dim3(1), dim3(BSZ), 0, stream, x, ws, out);
}

// Round 7
// 51.163 us; speedup vs baseline: 1.6382x; 1.6382x over previous
//
#include <hip/hip_runtime.h>
#include <math.h>

#define NBQ 50
#define S1 51
#define NPTS 2601      // 51*51
#define NTILES 163     // ceil(2601/16)
#define IN_D 64
#define HID 128
#define BSZ 256
#define NCHUNK 8
#define NUMAX 21       // max tiles per wave chunk

typedef __bf16 bf16x8 __attribute__((ext_vector_type(8)));
typedef float  f32x4  __attribute__((ext_vector_type(4)));

// ws layout (floats)
#define WS_CC     0                    // 51
#define WS_STEPS  64                   // 51
#define WS_XMAX   128                  // 1
#define WS_BASE   256                  // 256*128 = 32768
#define WS_SCAL   33024                // 256
#define WS_OFF    33280                // 256
#define WS_PART   33536                // 2048 (256 b * 8 chunks)
#define WS_W1BF   35840                // 16384 bf16 = 8192 floats

// ---------------- prep: w1 fragment conversion + cc/steps/xmax + base + n-net
__global__ void k_prep(const float* __restrict__ x, const float* __restrict__ h,
                       const float* __restrict__ iw0, const float* __restrict__ ib0,
                       const float* __restrict__ iw1,
                       const float* __restrict__ nw0, const float* __restrict__ nb0,
                       const float* __restrict__ nw1, const float* __restrict__ nb1,
                       const float* __restrict__ nw2, const float* __restrict__ nb2,
                       float* __restrict__ ws) {
    int blk = blockIdx.x;
    int tid = threadIdx.x;

    if (blk < 64) {
        // A-frag order: idx = ((NT*4+kk)*64 + lane)*8 + e
        //  value = iw1[(kk*32 + (lane>>4)*8 + e)*128 + NT*16 + (lane&15)]
        int idx  = blk * 256 + tid;      // 0..16383
        int e    = idx & 7;
        int lane = (idx >> 3) & 63;
        int fk   = idx >> 9;             // 0..31
        int kk   = fk & 3;
        int nt   = fk >> 2;
        int k = kk * 32 + (lane >> 4) * 8 + e;
        int n = nt * 16 + (lane & 15);
        __bf16* w1bf = (__bf16*)(ws + WS_W1BF);
        w1bf[idx] = (__bf16)iw1[k * HID + n];
        return;
    }

    __shared__ float s_steps[S1];
    __shared__ float s_red[4];
    __shared__ float s_h[IN_D - 1];
    __shared__ float s_o0[HID];
    __shared__ float s_part[4];

    if (blk == 64) {
        int t = tid;
        if (t < S1) {
            double st = cos((double)t * M_PI / (double)NBQ);
            s_steps[t] = (float)st;
            ws[WS_STEPS + t] = (float)st;
            double acc = 0.0;
            for (int i = 0; i <= NBQ; ++i) {
                double Wi;
                if (i == 0)       Wi = 1.0;
                else if (i & 1)   Wi = 0.0;
                else              Wi = 2.0 / (1.0 - (double)i * (double)i);
                double lam;
                if (t == 0)  lam = 0.5;
                else         lam = cos((double)i * (double)t * M_PI / (double)NBQ);
                if (t == NBQ) lam *= 0.5;
                lam *= 2.0 / (double)NBQ;
                acc += lam * Wi;
            }
            ws[WS_CC + t] = (float)acc;
        }
        __syncthreads();
        float xb = x[t];
        float m = -1e30f;
        for (int i = 0; i < S1; ++i)
            m = fmaxf(m, xb * (s_steps[i] + 1.0f) * 0.5f);
        for (int off = 32; off > 0; off >>= 1)
            m = fmaxf(m, __shfl_down(m, off));
        if ((t & 63) == 0) s_red[t >> 6] = m;
        __syncthreads();
        if (t == 0) {
            float mm = fmaxf(fmaxf(s_red[0], s_red[1]), fmaxf(s_red[2], s_red[3]));
            ws[WS_XMAX] = mm + 10.0f;
        }
        return;
    }

    // ---- base[b] + n-network: b = blk - 65, first 128 threads active ----
    int b = blk - 65;
    int n = tid;
    bool act = (n < HID);
    if (act && n < IN_D - 1) s_h[n] = h[b * (IN_D - 1) + n];
    __syncthreads();
    float o1 = 0.0f;
    if (act) {
        float accB = ib0[n];
        float acc0 = nb0[n];
        for (int d = 0; d < IN_D - 1; ++d) {
            float hv = s_h[d];
            accB = fmaf(hv, iw0[(1 + d) * HID + n], accB);
            acc0 = fmaf(hv, nw0[d * HID + n], acc0);
        }
        ws[WS_BASE + b * HID + n] = accB;
        s_o0[n] = fmaxf(acc0, 0.0f);
    }
    __syncthreads();
    if (act) {
        float acc1 = nb1[n];
        for (int m = 0; m < HID; ++m)
            acc1 = fmaf(s_o0[m], nw1[m * HID + n], acc1);
        o1 = fmaxf(acc1, 0.0f);
    }
    float p0 = act ? o1 * nw2[n * 2 + 0] : 0.0f;
    float p1 = act ? o1 * nw2[n * 2 + 1] : 0.0f;
    for (int off = 32; off > 0; off >>= 1) {
        p0 += __shfl_down(p0, off);
        p1 += __shfl_down(p1, off);
    }
    int lane = tid & 63, w = tid >> 6;
    if (lane == 0 && w < 2) { s_part[w * 2] = p0; s_part[w * 2 + 1] = p1; }
    __syncthreads();
    if (tid == 0) {
        ws[WS_OFF + b]  = s_part[0] + s_part[2] + nb2[0];
        ws[WS_SCAL + b] = expf(s_part[1] + s_part[3] + nb2[1]);
    }
}

// ---------------- main MFMA kernel: batched tail + pipelined geometry -------
// 1-wave blocks. Main loop has NO cross-lane ops: per-lane 16-n partial z goes
// to LDS; phase 2 sums the 4 g-partials, applies elu+1 and cc weights in bulk.
__global__ __launch_bounds__(64, 1) void k3_mfma(
        const float* __restrict__ x,
        const float* __restrict__ iw0,   // row 0 = w0 (128 floats)
        const float* __restrict__ ib1,
        const float* __restrict__ iw2,
        const float* __restrict__ ib2,
        float* __restrict__ ws) {
    __shared__ float s_cc[S1];
    __shared__ float s_ti[S1];
    __shared__ float s_w[S1];
    __shared__ float s_sjh[S1];
    __shared__ float s_ccw[S1];
    __shared__ float zlds[NUMAX][68];   // pad 68 to break bank aliasing in phase 2

    int blk  = blockIdx.x;
    int b    = blk >> 3;
    int c    = blk & 7;
    int lane = threadIdx.x;          // 0..63
    int col  = lane & 15;
    int g    = lane >> 4;            // 0..3

    float xmax = ws[WS_XMAX];
    float xb   = x[b];
    float b2   = ib2[0];

    if (lane < S1) {
        float st = ws[WS_STEPS + lane];
        float cc = ws[WS_CC + lane];
        float ti = xb * (st + 1.0f) * 0.5f;
        float w  = xmax - ti;
        s_cc[lane]  = cc;
        s_ti[lane]  = ti;
        s_w[lane]   = w;
        s_sjh[lane] = (st + 1.0f) * 0.5f;
        s_ccw[lane] = cc * w;
    }

    // W1 A-fragments: 8 nt x 4 kk x 8 bf16 = 128 regs
    const bf16x8* w1f = (const bf16x8*)(ws + WS_W1BF);
    bf16x8 Af[8][4];
#pragma unroll
    for (int nt = 0; nt < 8; ++nt)
#pragma unroll
        for (int kk = 0; kk < 4; ++kk)
            Af[nt][kk] = w1f[(nt * 4 + kk) * 64 + lane];

    // per-lane w0/base for m = kk*32 + g*8 + e : 64 regs
    const float* basep = ws + WS_BASE + b * HID;
    f32x4 w0a[4], w0b[4], bsa[4], bsb[4];
#pragma unroll
    for (int kk = 0; kk < 4; ++kk) {
        int m0 = kk * 32 + g * 8;
        w0a[kk] = *(const f32x4*)(iw0 + m0);
        w0b[kk] = *(const f32x4*)(iw0 + m0 + 4);
        bsa[kk] = *(const f32x4*)(basep + m0);
        bsb[kk] = *(const f32x4*)(basep + m0 + 4);
    }

    // per-lane ib1 (MFMA C-init) and iw2, n = nt*16 + g*4 + q : 64 regs
    f32x4 accInit[8], iw2v[8];
#pragma unroll
    for (int nt = 0; nt < 8; ++nt) {
        accInit[nt] = *(const f32x4*)(ib1 + nt * 16 + g * 4);
        iw2v[nt]    = *(const f32x4*)(iw2 + nt * 16 + g * 4);
    }

    __syncthreads();

    int NU = (c <= 2) ? 21 : 20;     // tiles this chunk: t = c + 8u

    // prologue geometry for u = 0
    {
        // nothing: computed inside loop via s_cur primed here
    }
    int pc0 = c * 16 + col;
    if (pc0 >= NPTS) pc0 = NPTS - 1;
    int i_c = (int)(((unsigned)pc0 * 10281u) >> 19);
    int j_c = pc0 - i_c * 51;
    float s_cur = fmaf(s_w[i_c], s_sjh[j_c], s_ti[i_c]);

    for (int u = 0; u < NU; ++u) {
        // build the 4 k-step B-fragments from s_cur
        bf16x8 bfr[4];
#pragma unroll
        for (int kk = 0; kk < 4; ++kk) {
#pragma unroll
            for (int e = 0; e < 4; ++e) {
                bfr[kk][e]     = (__bf16)fmaxf(fmaf(s_cur, w0a[kk][e], bsa[kk][e]), 0.0f);
                bfr[kk][4 + e] = (__bf16)fmaxf(fmaf(s_cur, w0b[kk][e], bsb[kk][e]), 0.0f);
            }
        }

        // pipeline: next tile's geometry issued before the MFMA block
        int t2 = c + 8 * (u + 1);
        int pc2 = t2 * 16 + col;
        if (pc2 >= NPTS) pc2 = NPTS - 1;
        int i_n = (int)(((unsigned)pc2 * 10281u) >> 19);
        int j_n = pc2 - i_n * 51;
        float s_nxt = fmaf(s_w[i_n], s_sjh[j_n], s_ti[i_n]);

        f32x4 acc[8];
#pragma unroll
        for (int kk = 0; kk < 4; ++kk)
#pragma unroll
            for (int nt = 0; nt < 8; ++nt)
                acc[nt] = __builtin_amdgcn_mfma_f32_16x16x32_bf16(
                    Af[nt][kk], bfr[kk], (kk == 0) ? accInit[nt] : acc[nt], 0, 0, 0);

        // per-lane 16-n partial (4 independent chains of depth 8)
        float z0 = 0.f, z1 = 0.f, z2 = 0.f, z3 = 0.f;
#pragma unroll
        for (int nt = 0; nt < 8; ++nt) {
            z0 = fmaf(fmaxf(acc[nt][0], 0.0f), iw2v[nt][0], z0);
            z1 = fmaf(fmaxf(acc[nt][1], 0.0f), iw2v[nt][1], z1);
            z2 = fmaf(fmaxf(acc[nt][2], 0.0f), iw2v[nt][2], z2);
            z3 = fmaf(fmaxf(acc[nt][3], 0.0f), iw2v[nt][3], z3);
        }
        zlds[u][g * 16 + col] = (z0 + z1) + (z2 + z3);

        s_cur = s_nxt;
    }

    // ---- phase 2: bulk tail. 64 lanes process 4 tiles (64 points) per pass.
    float vsum = 0.0f;
    int npass = (NU + 3) >> 2;
    for (int pass = 0; pass < npass; ++pass) {
        int u = pass * 4 + g;
        if (u < NU) {
            int t = c + 8 * u;
            int p = t * 16 + col;
            if (p < NPTS) {
                float z = zlds[u][col] + zlds[u][16 + col]
                        + zlds[u][32 + col] + zlds[u][48 + col] + b2;
                float f = (z > 0.0f) ? (z + 1.0f) : __expf(z);
                int i = (int)(((unsigned)p * 10281u) >> 19);
                int j = p - i * 51;
                vsum += s_ccw[i] * s_cc[j] * f;
            }
        }
    }

    // wave reduction; inner weight /2 -> x0.5 (each point counted once now)
#pragma unroll
    for (int off = 1; off < 64; off <<= 1)
        vsum += __shfl_xor(vsum, off);
    if (lane == 0)
        ws[WS_PART + blk] = vsum * 0.5f;
}

// ---------------- final: out[b] = scal*(sum parts)*x/2 + off ----------------
__global__ void k4_final(const float* __restrict__ x, const float* __restrict__ ws,
                         float* __restrict__ out) {
    int b = threadIdx.x;
    float sum = 0.0f;
#pragma unroll
    for (int c = 0; c < NCHUNK; ++c) sum += ws[WS_PART + b * NCHUNK + c];
    out[b] = ws[WS_SCAL + b] * sum * x[b] * 0.5f + ws[WS_OFF + b];
}

extern "C" void kernel_launch(void* const* d_in, const int* in_sizes, int n_in,
                              void* d_out, int out_size, void* d_ws, size_t ws_size,
                              hipStream_t stream) {
    const float* x   = (const float*)d_in[0];
    const float* h   = (const float*)d_in[1];
    const float* iw0 = (const float*)d_in[2];
    const float* ib0 = (const float*)d_in[3];
    const float* iw1 = (const float*)d_in[4];
    const float* ib1 = (const float*)d_in[5];
    const float* iw2 = (const float*)d_in[6];
    const float* ib2 = (const float*)d_in[7];
    const float* nw0 = (const float*)d_in[8];
    const float* nb0 = (const float*)d_in[9];
    const float* nw1 = (const float*)d_in[10];
    const float* nb1 = (const float*)d_in[11];
    const float* nw2 = (const float*)d_in[12];
    const float* nb2 = (const float*)d_in[13];
    float* ws  = (float*)d_ws;
    float* out = (float*)d_out;

    hipLaunchKernelGGL(k_prep, dim3(64 + 1 + BSZ), dim3(256), 0, stream,
                       x, h, iw0, ib0, iw1, nw0, nb0, nw1, nb1, nw2, nb2, ws);
    hipLaunchKernelGGL(k3_mfma, dim3(BSZ * NCHUNK), dim3(64), 0, stream,
                       x, iw0, ib1, iw2, ib2, ws);
    hipLaunchKernelGGL(k4_final, dim3(1), dim3(BSZ), 0, stream, x, ws, out);
}